// Round 3
// baseline (203.273 us; speedup 1.0000x reference)
//
#include <hip/hip_runtime.h>

// Problem constants (from reference): S=16, P=65536, N=256, K=32
#define S_DIM 16
#define P_DIM 65536
#define N_ROWS 256
#define K_IDX 32
#define NP ((size_t)N_ROWS * P_DIM)   // elements per channel
#define W_CHUNK 16384                 // p-range per block (4 chunks per row)

// ---------------------------------------------------------------------------
// Fused zero-fill + scatter. Block b owns row n = b>>2, p-range
// [p0, p0+W_CHUNK) with p0 = (b&3)*W_CHUNK, across all 3 channels.
//  1) threads 0..31 load the row's 32 indices into LDS
//  2) threads 0..31 compute count (32 compares vs LDS) and the 3 channel
//     values 1-(1-v_c)^cnt by exact repeated multiply (kept in registers)
//  3) all 256 threads zero-fill the 3 x W_CHUNK tile with float4 stores
//  4) __syncthreads(), then threads 0..31 overwrite their (n,p) position if
//     it lies in this block's chunk. Intra-block WAW ordered by the barrier;
//     duplicate indices write identical values (benign).
// ---------------------------------------------------------------------------
__global__ void fused_fill_scatter(const float* __restrict__ schema_params, // (S,P,4)
                                   const int* __restrict__ schema_ids,      // (N)
                                   const int* __restrict__ indices,         // (N,K)
                                   float* __restrict__ out) {               // (3,N,P)
    __shared__ int s_p[K_IDX];

    const int t  = threadIdx.x;            // 0..255
    const int n  = blockIdx.x >> 2;        // row
    const int p0 = (blockIdx.x & 3) * W_CHUNK;

    if (t < K_IDX) s_p[t] = indices[n * K_IDX + t];
    __syncthreads();

    // Per-thread scatter value (threads 0..31 only), kept in registers.
    float v0 = 0.f, v1 = 0.f, v2 = 0.f;
    int   p  = -1;
    if (t < K_IDX) {
        p = s_p[t];
        int cnt = 0;
#pragma unroll
        for (int j = 0; j < K_IDX; ++j) cnt += (s_p[j] == p) ? 1 : 0;

        const int s = schema_ids[n];
        const float4 f = *reinterpret_cast<const float4*>(
            schema_params + ((size_t)s * P_DIM + (size_t)p) * 4);

        // PROJ rows: c0 = f2 + f3, c1 = f1, c2 = f3
        const float b0 = 1.0f - (f.z + f.w);
        const float b1 = 1.0f - f.y;
        const float b2 = 1.0f - f.w;
        float r0 = 1.0f, r1 = 1.0f, r2 = 1.0f;
        for (int i = 0; i < cnt; ++i) { r0 *= b0; r1 *= b1; r2 *= b2; }
        v0 = 1.0f - r0; v1 = 1.0f - r1; v2 = 1.0f - r2;
    }

    // Zero-fill this block's tile: 3 channels x W_CHUNK floats, float4 stores.
    const float4 z = make_float4(0.f, 0.f, 0.f, 0.f);
    const size_t row_off = (size_t)n * P_DIM + (size_t)p0;
#pragma unroll
    for (int c = 0; c < 3; ++c) {
        float4* o4 = reinterpret_cast<float4*>(out + (size_t)c * NP + row_off);
#pragma unroll
        for (int i = 0; i < W_CHUNK / 4 / 256; ++i) {  // 16 iters
            o4[i * 256 + t] = z;
        }
    }

    __syncthreads();  // order fill stores before patch stores (intra-block WAW)

    if (t < K_IDX && p >= p0 && p < p0 + W_CHUNK) {
        const size_t off = (size_t)n * P_DIM + (size_t)p;
        out[off]          = v0;
        out[NP + off]     = v1;
        out[2 * NP + off] = v2;
    }
}

extern "C" void kernel_launch(void* const* d_in, const int* in_sizes, int n_in,
                              void* d_out, int out_size, void* d_ws, size_t ws_size,
                              hipStream_t stream) {
    const float* schema_params = (const float*)d_in[0]; // (16, 65536, 4) f32
    const int*   schema_ids    = (const int*)d_in[1];   // (256,) i32
    const int*   indices       = (const int*)d_in[2];   // (256, 32) i32
    float*       out           = (float*)d_out;         // (3, 256, 65536) f32 concat

    // One fused dispatch: 256 rows x 4 chunks = 1024 blocks of 256 threads.
    fused_fill_scatter<<<N_ROWS * 4, 256, 0, stream>>>(
        schema_params, schema_ids, indices, out);
}